// Round 3
// baseline (66.391 us; speedup 1.0000x reference)
//
#include <hip/hip_runtime.h>
#include <stdint.h>

// CompressedInteractionNet: out[b,k,d] = sum_v (x0r Vm[k])[d,v] * (xhr VhT[k])[d,v]
// Two-kernel plan:
//   prep: dtype-sense (fp32 vs bf16) + convert + transpose into d_ws (all bf16):
//         x0T[b][d][i] = x0[b][i][d]   (kills the stride-16 A-gather)
//         x0c          = x0 flat       (contig A2)
//         vmT[k][v][i] = Vm[k][i][v]   (kills the stride-16 B-gather)
//         vhc          = Vh flat       (contig B2)
//   main: per wave, 4 k's: 20 contiguous 16B bf8 loads + 16 mfma_16x16x32_bf16
//         + 16-lane xor-shuffle v-reduction. No LDS, no scalar gathers.

typedef __attribute__((ext_vector_type(8))) short bf8;  // 8 bf16 (4 VGPRs)
typedef __attribute__((ext_vector_type(4))) float f4;   // mfma C/D frag

#define NM 64   // m == H
#define ND 16   // D
#define NK 64   // Hk
#define NV 16   // vk

__device__ __forceinline__ unsigned short f2bf(float f) {
    union { float f; unsigned u; } x; x.f = f;
    return (unsigned short)((x.u + 0x8000u) >> 16);
}

__device__ __forceinline__ bool senseBF16(const void* x0) {
    // Low ushort viewed as bf16: real bf16 N(0,1) has exp in (100,150) ~always;
    // fp32 low-mantissa bits are ~uniform -> ~19% hit rate. Wave-uniform.
    unsigned u  = ((const unsigned*)x0)[threadIdx.x & 63];
    unsigned ex = (u >> 7) & 0xffu;
    bool inr    = (ex > 100u && ex < 150u);
    return __popcll(__ballot(inr)) >= 48;
}

template <bool FP32>
__device__ __forceinline__ void prep_body(const void* __restrict__ x0,
                                          const void* __restrict__ vm,
                                          const void* __restrict__ vh,
                                          unsigned short* __restrict__ ws,
                                          int t, int nx0, int nvm) {
    const void* p;
    int src;
    if (t < nx0) {                       // x0T[b][d][i] = x0[b][i][d]
        int b = t >> 10, rem = t & 1023, d = rem >> 6, i = rem & 63;
        src = b * 1024 + i * 16 + d;  p = x0;
    } else if (t < 2 * nx0) {            // x0c flat
        src = t - nx0;  p = x0;
    } else if (t < 2 * nx0 + nvm) {      // vmT[k][v][i] = Vm[k][i][v]
        int s = t - 2 * nx0;
        int k = s >> 10, rem = s & 1023, v = rem >> 6, i = rem & 63;
        src = k * 1024 + i * 16 + v;  p = vm;
    } else {                             // vhc flat
        src = t - (2 * nx0 + nvm);  p = vh;
    }
    unsigned short o;
    if (FP32) o = f2bf(((const float*)p)[src]);
    else      o = ((const unsigned short*)p)[src];
    ws[t] = o;
}

__global__ void __launch_bounds__(256) cin_prep(const void* __restrict__ x0,
                                                const void* __restrict__ vm,
                                                const void* __restrict__ vh,
                                                unsigned short* __restrict__ ws,
                                                int nx0, int nvm, int total) {
    int t = blockIdx.x * 256 + threadIdx.x;
    bool isbf16 = senseBF16(x0);
    if (t >= total) return;
    if (isbf16) prep_body<false>(x0, vm, vh, ws, t, nx0, nvm);
    else        prep_body<true>(x0, vm, vh, ws, t, nx0, nvm);
}

__global__ void __launch_bounds__(256) cin_main(const unsigned short* __restrict__ ws,
                                                const void* __restrict__ x0,
                                                void* __restrict__ out,
                                                int nx0, int nvm) {
    const int tid    = threadIdx.x;
    const int l      = tid & 63;
    const int w      = tid >> 6;       // wave 0..3
    const int lane16 = l & 15;
    const int quad   = l >> 4;
    const int b      = blockIdx.x >> 2;
    const int kg     = (blockIdx.x & 3) * 4 + w;   // 0..15, 4 k's each

    const bool isbf16 = senseBF16(x0);

    // All fragments: element offset = lane16*64 + s*32 + quad*8 within a 1024-tile
    // -> bf8 index lane16*8 + s*4 + quad (16B-aligned contiguous loads).
    const int fi0 = lane16 * 8 + quad;       // s = 0
    const int fi1 = fi0 + 4;                 // s = 1

    const unsigned short* x0t = ws + b * 1024;          // x0T tile
    const unsigned short* x0c = ws + nx0 + b * 1024;    // x0 flat tile
    const unsigned short* vmt = ws + 2 * nx0;           // vmT base
    const unsigned short* vhc = ws + 2 * nx0 + nvm;     // vh flat base

    // A layout (16x16x32): A[m = lane16][k = quad*8 + e + s*32]
    bf8 a1[2], a2[2];
    a1[0] = ((const bf8*)x0t)[fi0];  a1[1] = ((const bf8*)x0t)[fi1];
    a2[0] = ((const bf8*)x0c)[fi0];  a2[1] = ((const bf8*)x0c)[fi1];

#pragma unroll
    for (int kk = 0; kk < 4; ++kk) {
        const int k = kg * 4 + kk;
        // B layout (16x16x32): B[k = quad*8 + e + s*32][n = lane16]
        const bf8* b1p = (const bf8*)(vmt + k * 1024);
        const bf8* b2p = (const bf8*)(vhc + k * 1024);
        bf8 b1_0 = b1p[fi0], b1_1 = b1p[fi1];
        bf8 b2_0 = b2p[fi0], b2_1 = b2p[fi1];

        f4 ac = {0.f, 0.f, 0.f, 0.f}, bc = {0.f, 0.f, 0.f, 0.f};
        ac = __builtin_amdgcn_mfma_f32_16x16x32_bf16(a1[0], b1_0, ac, 0, 0, 0);
        bc = __builtin_amdgcn_mfma_f32_16x16x32_bf16(a2[0], b2_0, bc, 0, 0, 0);
        ac = __builtin_amdgcn_mfma_f32_16x16x32_bf16(a1[1], b1_1, ac, 0, 0, 0);
        bc = __builtin_amdgcn_mfma_f32_16x16x32_bf16(a2[1], b2_1, bc, 0, 0, 0);

        // C/D layout: reg r at lane l = C[row = quad*4 + r][col = lane16]
        // out[b,k,d] for d = quad*4 + r; v-sum over lane16 within each 16-group.
        float p0 = ac[0] * bc[0], p1 = ac[1] * bc[1];
        float p2 = ac[2] * bc[2], p3 = ac[3] * bc[3];
#pragma unroll
        for (int off = 1; off < 16; off <<= 1) {
            p0 += __shfl_xor(p0, off);
            p1 += __shfl_xor(p1, off);
            p2 += __shfl_xor(p2, off);
            p3 += __shfl_xor(p3, off);
        }
        if (lane16 == 0) {
            const int ob = b * (NK * ND) + k * ND + quad * 4;
            if (isbf16) {
                ushort4 o;
                o.x = f2bf(p0); o.y = f2bf(p1); o.z = f2bf(p2); o.w = f2bf(p3);
                *(ushort4*)((unsigned short*)out + ob) = o;  // 8B aligned
            } else {
                f4 o = {p0, p1, p2, p3};
                *(f4*)((float*)out + ob) = o;                // 16B aligned
            }
        }
    }
}

extern "C" void kernel_launch(void* const* d_in, const int* in_sizes, int n_in,
                              void* d_out, int out_size, void* d_ws, size_t ws_size,
                              hipStream_t stream) {
    const int nx0 = in_sizes[0];            // 131072 (B*m*D)
    const int nvm = in_sizes[2];            // 65536  (Hk*m*vk)
    const int nvh = in_sizes[3];            // 65536
    const int nb  = nx0 / (NM * ND);        // batch = 128
    const int total = 2 * nx0 + nvm + nvh;  // 393216 ushorts = 768 KB in ws

    unsigned short* ws = (unsigned short*)d_ws;
    cin_prep<<<dim3((total + 255) / 256), dim3(256), 0, stream>>>(
        d_in[0], d_in[2], d_in[3], ws, nx0, nvm, total);
    cin_main<<<dim3(nb * 4), dim3(256), 0, stream>>>(
        ws, d_in[0], d_out, nx0, nvm);
}

// Round 4
// 64.802 us; speedup vs baseline: 1.0245x; 1.0245x over previous
//
#include <hip/hip_runtime.h>
#include <stdint.h>

// CompressedInteractionNet: out[b,k,d] = sum_v (x0r Vm[k])[d,v] * (xhr VhT[k])[d,v]
//   x0r[d][i] = x_0[b][i][d]                      (stride-16 gather)
//   xhr[d][j] = x_0 flat [b*1024 + d*64 + j]      (contiguous; m == H source bug)
// One wave per (b, 4 k's). Two mfma_f32_16x16x32_bf16 per 16x64@64x16 product.
// Input dtype sensed at runtime (bf16 vs fp32); output dtype matches input.
//
// NOTE (R3 post-mortem): total dur_us ≈ 65 µs is dominated by harness resets
// (268 MB ws 0xAA poison = 40 µs @ 83% HBM peak + input restores). A two-kernel
// pre-staged variant measured 66.4 vs this one's 65.3 — this single-dispatch,
// no-ws version is the best measured configuration.

typedef __attribute__((ext_vector_type(8))) short bf8;  // 8 bf16 values (4 VGPRs)
typedef __attribute__((ext_vector_type(4))) float f4;   // mfma C/D frag

#define NM 64   // m == H
#define ND 16   // D
#define NK 64   // Hk
#define NV 16   // vk

__device__ __forceinline__ unsigned short f2bf(float f) {
    union { float f; unsigned u; } x; x.f = f;
    return (unsigned short)((x.u + 0x8000u) >> 16);
}

template <bool FP32>
__device__ __forceinline__ bf8 gatherFrag(const void* p, int base) {
    // frag element e lives at flat index base + e*16
    bf8 r;
    if (FP32) {
        const float* q = (const float*)p + base;
#pragma unroll
        for (int e = 0; e < 8; ++e) r[e] = (short)f2bf(q[e * 16]);
    } else {
        const unsigned short* q = (const unsigned short*)p + base;
#pragma unroll
        for (int e = 0; e < 8; ++e) r[e] = (short)q[e * 16];
    }
    return r;
}

template <bool FP32>
__device__ __forceinline__ bf8 contigFrag(const void* p, int base) {
    // frag elements are 8 consecutive values starting at base (base % 8 == 0)
    bf8 r;
    if (FP32) {
        const f4* q = (const f4*)((const float*)p + base);
        f4 lo = q[0], hi = q[1];
#pragma unroll
        for (int e = 0; e < 4; ++e) {
            r[e]     = (short)f2bf(lo[e]);
            r[e + 4] = (short)f2bf(hi[e]);
        }
    } else {
        r = *(const bf8*)((const unsigned short*)p + base);
    }
    return r;
}

template <bool FP32>
__device__ __forceinline__ void run(const void* __restrict__ x0,
                                    const void* __restrict__ vm,
                                    const void* __restrict__ vh,
                                    void* __restrict__ out) {
    const int l      = threadIdx.x;   // 0..63
    const int lane16 = l & 15;
    const int quad   = l >> 4;
    const int b      = blockIdx.x >> 4;
    const int kg     = blockIdx.x & 15;

    const int xb = b * (NM * ND);  // 1024 elements per batch

    // A-frags, reused across all 4 k's.
    // A layout (16x16x32): A[m = lane&15][k = quad*8 + e]
    bf8 a1[2], a2[2];
#pragma unroll
    for (int s = 0; s < 2; ++s) {
        // x0r[d][i], d = lane16, i = s*32 + quad*8 + e  -> flat xb + i*16 + d
        a1[s] = gatherFrag<FP32>(x0, xb + (s * 32 + quad * 8) * 16 + lane16);
        // xhr[d][j], d = lane16, j = s*32 + quad*8 + e  -> flat xb + d*64 + j
        a2[s] = contigFrag<FP32>(x0, xb + lane16 * 64 + s * 32 + quad * 8);
    }

#pragma unroll
    for (int kk = 0; kk < 4; ++kk) {
        const int k  = kg * 4 + kk;
        const int wb = k * (NM * NV);  // 1024 elements per k in Vm and Vh

        // B layout (16x16x32): B[k = quad*8 + e][n = lane&15]
        bf8 b1[2], b2[2];
#pragma unroll
        for (int s = 0; s < 2; ++s) {
            // Vm[k][i][v]: i = s*32+quad*8+e (K), v = lane16 (N) -> flat wb + i*16 + v
            b1[s] = gatherFrag<FP32>(vm, wb + (s * 32 + quad * 8) * 16 + lane16);
            // VhT[j][v] = Vh[k][v][j]: j = s*32+quad*8+e (K), v = lane16 -> flat wb + v*64 + j
            b2[s] = contigFrag<FP32>(vh, wb + lane16 * 64 + s * 32 + quad * 8);
        }

        f4 ac = {0.f, 0.f, 0.f, 0.f}, bc = {0.f, 0.f, 0.f, 0.f};
#pragma unroll
        for (int s = 0; s < 2; ++s) {
            ac = __builtin_amdgcn_mfma_f32_16x16x32_bf16(a1[s], b1[s], ac, 0, 0, 0);
            bc = __builtin_amdgcn_mfma_f32_16x16x32_bf16(a2[s], b2[s], bc, 0, 0, 0);
        }

        // C/D layout: reg r at lane l = C[row = quad*4 + r][col = lane16]
        // out[b,k,d] for d = quad*4 + r; sum over v = lane16 within each 16-group
        float p0 = ac[0] * bc[0], p1 = ac[1] * bc[1];
        float p2 = ac[2] * bc[2], p3 = ac[3] * bc[3];
#pragma unroll
        for (int off = 1; off < 16; off <<= 1) {
            p0 += __shfl_xor(p0, off);
            p1 += __shfl_xor(p1, off);
            p2 += __shfl_xor(p2, off);
            p3 += __shfl_xor(p3, off);
        }
        if (lane16 == 0) {
            const int ob = b * (NK * ND) + k * ND + quad * 4;
            if (FP32) {
                f4 w = {p0, p1, p2, p3};
                *(f4*)((float*)out + ob) = w;              // 16B aligned
            } else {
                ushort4 w;
                w.x = f2bf(p0); w.y = f2bf(p1); w.z = f2bf(p2); w.w = f2bf(p3);
                *(ushort4*)((unsigned short*)out + ob) = w; // 8B aligned
            }
        }
    }
}

__global__ void __launch_bounds__(64) cin_kernel(const void* __restrict__ x0,
                                                 const void* __restrict__ vm,
                                                 const void* __restrict__ vh,
                                                 void* __restrict__ out) {
    // Runtime input-dtype sense (wave-uniform). Key insight: the fp32-view
    // exponent of packed-bf16 data equals the high bf16's exponent, so test the
    // LOW ushort as bf16 instead: real bf16 N(0,1) has exp in (100,150) ~always;
    // fp32 mantissa bits are uniform -> ~19% hit rate.
    unsigned u  = ((const unsigned*)x0)[threadIdx.x];
    unsigned ex = (u >> 7) & 0xffu;  // exponent field of LOW ushort as bf16
    bool inr    = (ex > 100u && ex < 150u);
    bool isbf16 = __popcll(__ballot(inr)) >= 48;
    if (isbf16) run<false>(x0, vm, vh, out);
    else        run<true>(x0, vm, vh, out);
}

extern "C" void kernel_launch(void* const* d_in, const int* in_sizes, int n_in,
                              void* d_out, int out_size, void* d_ws, size_t ws_size,
                              hipStream_t stream) {
    const int nb = in_sizes[0] / (NM * ND);  // batch = 128
    cin_kernel<<<dim3(nb * 16), dim3(64), 0, stream>>>(
        d_in[0], d_in[2], d_in[3], d_out);
}